// Round 9
// baseline (525.061 us; speedup 1.0000x reference)
//
#include <hip/hip_runtime.h>
#include <math.h>

typedef _Float16 h8f16 __attribute__((ext_vector_type(8)));
typedef _Float16 h2f16 __attribute__((ext_vector_type(2)));
typedef float f32x4 __attribute__((ext_vector_type(4)));

#define MFMA16(a, b, c) __builtin_amdgcn_mfma_f32_16x16x32_f16((a), (b), (c), 0, 0, 0)

__device__ __forceinline__ float silu_f(float v) {
    return v * __builtin_amdgcn_rcpf(1.0f + __expf(-v));
}

// Bare barrier: writer-side LDS completion + s_barrier (no vmcnt drain).
__device__ __forceinline__ void bar_lds() {
    asm volatile("s_waitcnt lgkmcnt(0)" ::: "memory");
    __builtin_amdgcn_s_barrier();
    __builtin_amdgcn_sched_barrier(0);
}

// ---------------------------------------------------------------------------
// ODE mega-kernel v9 = v6 + TWO independent 16-row groups per block.
// grid: 64 blocks (32 batch rows: group A = rows 0-15, group B = rows 16-31)
// x 512 threads (8 waves; wave w owns output cols [16w,16w+16) of BOTH groups).
// Within each barrier interval the wave executes phase(A) then phase(B);
// A,B are data-independent so their latencies overlap (compiler interleaves).
// Numerics identical to v6 (32 RK4 steps, f16 data plane, gamma/beta folded,
// fdot2 stats, bx streamed from global and never vmcnt-drained in the loop).
// ---------------------------------------------------------------------------
__global__ __launch_bounds__(512, 1) void ode_kernel(
    const float* __restrict__ past,
    const float* __restrict__ xproj_w, const float* __restrict__ xproj_b,
    const float* __restrict__ z0_w, const float* __restrict__ z0_b,
    const float* __restrict__ ln_g, const float* __restrict__ ln_b,
    const float* __restrict__ w1, const float* __restrict__ b1,
    const float* __restrict__ w2, const float* __restrict__ b2,
    const float* __restrict__ w3, const float* __restrict__ b3,
    float* __restrict__ zbuf)
{
    __shared__ _Float16 hbA[16][136], h1A[16][136], h2A[16][136];
    __shared__ _Float16 hbB[16][136], h1B[16][136], h2B[16][136];
    __shared__ float    pS[32][33];      // prologue
    __shared__ float    x0S[32][128];
    __shared__ float    zS0[32][129];

    const int tid  = threadIdx.x;
    const int wid  = tid >> 6;
    const int lane = tid & 63;
    const int lrow = lane & 15;
    const int lhi  = lane >> 4;
    const int b0   = blockIdx.x * 32;    // 32 rows per block
    const int nc   = wid * 16 + lrow;    // this lane's output col (all layers)
    const int koff = lhi * 8;

    // ---- weights into register B-fragments; gamma folded into W1a (v6) ----
    h8f16 w1f[4], wcf, w2f[4], w3f[4];
    float b1t, b2r, b3r;
    {
#pragma unroll
        for (int ks = 0; ks < 4; ++ks) {
            h8f16 v1, v2, v3;
#pragma unroll
            for (int j = 0; j < 8; ++j) {
                const int k = ks * 32 + koff + j;
                v1[j] = (_Float16)(w1[nc * 256 + k] * ln_g[k]);
                v2[j] = (_Float16)w2[nc * 128 + k];
                v3[j] = (_Float16)w3[nc * 128 + k];
            }
            w1f[ks] = v1; w2f[ks] = v2; w3f[ks] = v3;
        }
        float wc[8] = {0, 0, 0, 0, 0, 0, 0, 0};
        float bc = 0.0f, bb = 0.0f;
        const float* w1a = w1 + nc * 256;
        const float* w1b = w1a + 128;
#pragma unroll 4
        for (int k = 0; k < 128; ++k) {
            const float a = w1b[k];
            bc += a * xproj_b[k];
            bb += w1a[k] * ln_b[k];
            const float* xr = xproj_w + k * 32 + koff;
#pragma unroll
            for (int j = 0; j < 8; ++j) wc[j] += a * xr[j];
        }
        h8f16 v;
#pragma unroll
        for (int j = 0; j < 8; ++j) v[j] = (_Float16)wc[j];
        wcf = v;
        b1t = b1[nc] + bc + bb;
        b2r = b2[nc]; b3r = b3[nc];
    }

    // ---- prologue: z0 for 32 rows (exact f32) ----
    for (int i = tid; i < 32 * 32; i += 512)
        pS[i >> 5][i & 31] = past[(long)(b0 + (i >> 5)) * 16384 + (i & 31)];
    __syncthreads();
    {
        const int r  = tid >> 4;            // 0..31
        const int c0 = (tid & 15) * 8;
#pragma unroll
        for (int cc = 0; cc < 8; ++cc) {
            const int kc = c0 + cc;
            float s = xproj_b[kc];
            const float* xr = xproj_w + kc * 32;
#pragma unroll
            for (int c = 0; c < 32; ++c) s += pS[r][c] * xr[c];
            x0S[r][kc] = s;
        }
    }
    __syncthreads();
    {
        const int nn = tid & 127;
        const int r0 = (tid >> 7) * 8;      // 4 groups x 8 rows
        for (int p = 0; p < 8; ++p) {
            const int r = r0 + p;
            float s = z0_b[nn];
            const float* zr = z0_w + nn * 128;
            for (int k = 0; k < 128; ++k) s += x0S[r][k] * zr[k];
            zS0[r][nn] = s;
        }
    }
    __syncthreads();

    // ---- per-group state (C-frag layout: rows 4*lhi+j, col nc) ----
    float zcA[4], krkA[4], zcB[4], krkB[4];
#pragma unroll
    for (int j = 0; j < 4; ++j) {
        zcA[j] = zS0[4 * lhi + j][nc];
        zcB[j] = zS0[16 + 4 * lhi + j][nc];
        hbA[4 * lhi + j][nc] = (_Float16)zcA[j];
        hbB[4 * lhi + j][nc] = (_Float16)zcB[j];
    }

    const float DT = 1.0f / 32.0f;
    const h2f16 one2 = {(_Float16)1.0f, (_Float16)1.0f};

    // ---- bx streaming (per group; loads stay in flight across barriers) ----
    f32x4 sA0a, sA0b, sA1a, sA1b;
    f32x4 sB0a, sB0b, sB1a, sB1b;
    auto stageA = [&](int e) {
        const float pos = (float)e * 7.984375f;     // e*(511/64), exact
        const int i0 = (int)pos;
        const int i1 = (i0 < 511) ? i0 + 1 : 511;
        const float* base = past + (long)(b0 + lrow) * 16384;
        const float* p0 = base + i0 * 32 + koff;
        const float* p1 = base + i1 * 32 + koff;
        sA0a = *(const f32x4*)p0; sA0b = *(const f32x4*)(p0 + 4);
        sA1a = *(const f32x4*)p1; sA1b = *(const f32x4*)(p1 + 4);
    };
    auto stageB = [&](int e) {
        const float pos = (float)e * 7.984375f;
        const int i0 = (int)pos;
        const int i1 = (i0 < 511) ? i0 + 1 : 511;
        const float* base = past + (long)(b0 + 16 + lrow) * 16384;
        const float* p0 = base + i0 * 32 + koff;
        const float* p1 = base + i1 * 32 + koff;
        sB0a = *(const f32x4*)p0; sB0b = *(const f32x4*)(p0 + 4);
        sB1a = *(const f32x4*)p1; sB1b = *(const f32x4*)(p1 + 4);
    };
    auto blendA = [&](int e) -> h8f16 {
        const float pos = (float)e * 7.984375f;
        const float w = pos - floorf(pos);
        h8f16 r;
#pragma unroll
        for (int j = 0; j < 4; ++j) {
            r[j]     = (_Float16)(sA0a[j] + w * (sA1a[j] - sA0a[j]));
            r[4 + j] = (_Float16)(sA0b[j] + w * (sA1b[j] - sA0b[j]));
        }
        return r;
    };
    auto blendB = [&](int e) -> h8f16 {
        const float pos = (float)e * 7.984375f;
        const float w = pos - floorf(pos);
        h8f16 r;
#pragma unroll
        for (int j = 0; j < 4; ++j) {
            r[j]     = (_Float16)(sB0a[j] + w * (sB1a[j] - sB0a[j]));
            r[4 + j] = (_Float16)(sB0b[j] + w * (sB1b[j] - sB0b[j]));
        }
        return r;
    };

    // ---- phases (parameterized by group buffers) ----
    auto phaseA = [&](const _Float16 (*hb)[136], _Float16 (*h1)[136], h8f16 bx) {
        h8f16 xf[4];
#pragma unroll
        for (int ks = 0; ks < 4; ++ks)
            xf[ks] = *(const h8f16*)&hb[lrow][ks * 32 + koff];
        float s0 = 0.f, s1 = 0.f, q0 = 0.f, q1 = 0.f;
#pragma unroll
        for (int ks = 0; ks < 4; ++ks) {
#pragma unroll
            for (int p = 0; p < 4; ++p) {
                const h2f16 x2 = {xf[ks][2 * p], xf[ks][2 * p + 1]};
                if (p & 1) {
                    s1 = __builtin_amdgcn_fdot2(x2, one2, s1, false);
                    q1 = __builtin_amdgcn_fdot2(x2, x2, q1, false);
                } else {
                    s0 = __builtin_amdgcn_fdot2(x2, one2, s0, false);
                    q0 = __builtin_amdgcn_fdot2(x2, x2, q0, false);
                }
            }
        }
        float s = s0 + s1, q = q0 + q1;
        s += __shfl_xor(s, 16); q += __shfl_xor(q, 16);
        s += __shfl_xor(s, 32); q += __shfl_xor(q, 32);
        const float mu  = s * (1.0f / 128.0f);
        const float var = q * (1.0f / 128.0f) - mu * mu;
        const float inv = 1.0f / sqrtf(var + 1e-5f);
        const _Float16 ih = (_Float16)inv;
        const _Float16 mh = (_Float16)(-mu * inv);
        h8f16 ip, mp;
#pragma unroll
        for (int j = 0; j < 8; ++j) { ip[j] = ih; mp[j] = mh; }
        f32x4 acc = {0, 0, 0, 0};
#pragma unroll
        for (int ks = 0; ks < 4; ++ks) {
            const h8f16 az = xf[ks] * ip + mp;   // packed f16 LN-apply
            acc = MFMA16(az, w1f[ks], acc);
        }
        acc = MFMA16(bx, wcf, acc);
#pragma unroll
        for (int j = 0; j < 4; ++j)
            h1[4 * lhi + j][nc] = (_Float16)silu_f(acc[j] + b1t);
    };
    auto phaseB = [&](const _Float16 (*h1)[136], _Float16 (*h2)[136]) {
        f32x4 acc = {0, 0, 0, 0};
#pragma unroll
        for (int ks = 0; ks < 4; ++ks) {
            const h8f16 a = *(const h8f16*)&h1[lrow][ks * 32 + koff];
            acc = MFMA16(a, w2f[ks], acc);
        }
#pragma unroll
        for (int j = 0; j < 4; ++j)
            h2[4 * lhi + j][nc] = (_Float16)silu_f(acc[j] + b2r);
    };
    auto phaseC = [&](const _Float16 (*h2)[136]) -> f32x4 {
        f32x4 acc = {0, 0, 0, 0};
#pragma unroll
        for (int ks = 0; ks < 4; ++ks) {
            const h8f16 a = *(const h8f16*)&h2[lrow][ks * 32 + koff];
            acc = MFMA16(a, w3f[ks], acc);
        }
#pragma unroll
        for (int j = 0; j < 4; ++j) acc[j] += b3r;
        return acc;
    };

    stageA(0); stageB(0);
    h8f16 bxcA = blendA(0);
    h8f16 bxcB = blendB(0);
    __syncthreads();

#pragma unroll 1
    for (int st = 0; st < 32; ++st) {
        const int e1 = 2 * st + 1, e2 = 2 * st + 2;
        // ---- sub0: k1 ----
        phaseA(hbA, h1A, bxcA); phaseA(hbB, h1B, bxcB);
        stageA(e1); stageB(e1);
        bar_lds();
        phaseB(h1A, h2A); phaseB(h1B, h2B); bar_lds();
        {
            const f32x4 kA = phaseC(h2A);
            const f32x4 kB = phaseC(h2B);
#pragma unroll
            for (int j = 0; j < 4; ++j) {
                krkA[j] = kA[j];
                krkB[j] = kB[j];
                hbA[4 * lhi + j][nc] = (_Float16)(zcA[j] + 0.5f * DT * kA[j]);
                hbB[4 * lhi + j][nc] = (_Float16)(zcB[j] + 0.5f * DT * kB[j]);
            }
        }
        bar_lds();
        // ---- sub1: k2 ----
        bxcA = blendA(e1); bxcB = blendB(e1);
        phaseA(hbA, h1A, bxcA); phaseA(hbB, h1B, bxcB); bar_lds();
        phaseB(h1A, h2A); phaseB(h1B, h2B); bar_lds();
        {
            const f32x4 kA = phaseC(h2A);
            const f32x4 kB = phaseC(h2B);
#pragma unroll
            for (int j = 0; j < 4; ++j) {
                krkA[j] += 2.0f * kA[j];
                krkB[j] += 2.0f * kB[j];
                hbA[4 * lhi + j][nc] = (_Float16)(zcA[j] + 0.5f * DT * kA[j]);
                hbB[4 * lhi + j][nc] = (_Float16)(zcB[j] + 0.5f * DT * kB[j]);
            }
        }
        bar_lds();
        // ---- sub2: k3 ----
        phaseA(hbA, h1A, bxcA); phaseA(hbB, h1B, bxcB);
        stageA(e2); stageB(e2);
        bar_lds();
        phaseB(h1A, h2A); phaseB(h1B, h2B); bar_lds();
        {
            const f32x4 kA = phaseC(h2A);
            const f32x4 kB = phaseC(h2B);
#pragma unroll
            for (int j = 0; j < 4; ++j) {
                krkA[j] += 2.0f * kA[j];
                krkB[j] += 2.0f * kB[j];
                hbA[4 * lhi + j][nc] = (_Float16)(zcA[j] + DT * kA[j]);
                hbB[4 * lhi + j][nc] = (_Float16)(zcB[j] + DT * kB[j]);
            }
        }
        bar_lds();
        // ---- sub3: k4 + z update ----
        bxcA = blendA(e2); bxcB = blendB(e2);
        phaseA(hbA, h1A, bxcA); phaseA(hbB, h1B, bxcB); bar_lds();
        phaseB(h1A, h2A); phaseB(h1B, h2B); bar_lds();
        {
            const f32x4 kA = phaseC(h2A);
            const f32x4 kB = phaseC(h2B);
#pragma unroll
            for (int j = 0; j < 4; ++j) {
                zcA[j] += (DT / 6.0f) * (krkA[j] + kA[j]);
                zcB[j] += (DT / 6.0f) * (krkB[j] + kB[j]);
                hbA[4 * lhi + j][nc] = (_Float16)zcA[j];
                hbB[4 * lhi + j][nc] = (_Float16)zcB[j];
            }
        }
        bar_lds();
    }

#pragma unroll
    for (int j = 0; j < 4; ++j) {
        zbuf[(long)(b0 + 4 * lhi + j) * 128 + nc]      = zcA[j];
        zbuf[(long)(b0 + 16 + 4 * lhi + j) * 128 + nc] = zcB[j];
    }
}

// ---------------------------------------------------------------------------
// hcat = [x_t flat (3072) | cond (128) | time-emb (128)] as f16
// ---------------------------------------------------------------------------
__global__ __launch_bounds__(256) void hcat_kernel(
    const float* __restrict__ x_t, const float* __restrict__ cond,
    const int* __restrict__ tvals, _Float16* __restrict__ hcat)
{
    const int gid = blockIdx.x * 256 + threadIdx.x;
    const int b  = gid / 416;
    const int j0 = (gid % 416) * 8;
    h8f16 v;
    if (j0 < 3072) {
        const float* s = x_t + (long)b * 3072 + j0;
#pragma unroll
        for (int j = 0; j < 8; ++j) v[j] = (_Float16)s[j];
    } else if (j0 < 3200) {
        const float* s = cond + (long)b * 128 + (j0 - 3072);
#pragma unroll
        for (int j = 0; j < 8; ++j) v[j] = (_Float16)s[j];
    } else {
        const float tv = (float)tvals[b];
#pragma unroll
        for (int j = 0; j < 8; ++j) {
            const int jj  = j0 - 3200 + j;
            const int idx = (jj < 64) ? jj : jj - 64;
            const float fr = expf(-9.210340371976184f * (float)idx * (1.0f / 63.0f));
            const float a  = tv * fr;
            v[j] = (_Float16)((jj < 64) ? sinf(a) : cosf(a));
        }
    }
    *(h8f16*)&hcat[(long)b * 3328 + j0] = v;
}

// ---------------------------------------------------------------------------
// Generic f16-MFMA GEMM: out(M,N) = [silu](A(M,K) @ W(N,K).T + bias)
// ---------------------------------------------------------------------------
template <bool SILU, bool OUT_F16>
__global__ __launch_bounds__(256) void gemm_f16(
    const _Float16* __restrict__ A, const float* __restrict__ W,
    const float* __restrict__ bias, void* __restrict__ out,
    int M, int N, int K)
{
    __shared__ _Float16 aS[64][40];
    __shared__ _Float16 wS[64][40];
    const int mb = blockIdx.x * 64, nb = blockIdx.y * 64;
    const int tid = threadIdx.x, lane = tid & 63, wq = tid >> 6;
    const int lrow = lane & 15, lhi = lane >> 4;
    f32x4 acc[4];
#pragma unroll
    for (int nt = 0; nt < 4; ++nt) acc[nt] = (f32x4){0, 0, 0, 0};

    const int sr = tid >> 2;
    const int sk = (tid & 3) * 8;

    for (int k0 = 0; k0 < K; k0 += 32) {
        {
            h8f16 v = *(const h8f16*)&A[(long)(mb + sr) * K + k0 + sk];
            *(h8f16*)&aS[sr][sk] = v;
        }
        {
            const float* s = &W[(long)(nb + sr) * K + k0 + sk];
            h8f16 v;
#pragma unroll
            for (int j = 0; j < 8; ++j) v[j] = (_Float16)s[j];
            *(h8f16*)&wS[sr][sk] = v;
        }
        __syncthreads();
        h8f16 a = *(const h8f16*)&aS[wq * 16 + lrow][lhi * 8];
#pragma unroll
        for (int nt = 0; nt < 4; ++nt) {
            h8f16 bfr = *(const h8f16*)&wS[nt * 16 + lrow][lhi * 8];
            acc[nt] = MFMA16(a, bfr, acc[nt]);
        }
        __syncthreads();
    }

#pragma unroll
    for (int nt = 0; nt < 4; ++nt) {
        const int cc = nb + nt * 16 + lrow;
        const float bv = bias[cc];
#pragma unroll
        for (int j = 0; j < 4; ++j) {
            const int rr = mb + wq * 16 + lhi * 4 + j;
            float v = acc[nt][j] + bv;
            if (SILU) v = silu_f(v);
            if (OUT_F16) ((_Float16*)out)[(long)rr * N + cc] = (_Float16)v;
            else         ((float*)out)[(long)rr * N + cc] = v;
        }
    }
}

// ---------------------------------------------------------------------------
extern "C" void kernel_launch(void* const* d_in, const int* in_sizes, int n_in,
                              void* d_out, int out_size, void* d_ws, size_t ws_size,
                              hipStream_t stream)
{
    const float* x_t     = (const float*)d_in[0];
    const float* past    = (const float*)d_in[1];
    const int*   tvals   = (const int*)d_in[2];
    const float* xproj_w = (const float*)d_in[3];
    const float* xproj_b = (const float*)d_in[4];
    const float* z0_w    = (const float*)d_in[5];
    const float* z0_b    = (const float*)d_in[6];
    const float* ln_g    = (const float*)d_in[7];
    const float* ln_b    = (const float*)d_in[8];
    const float* w1      = (const float*)d_in[9];
    const float* b1      = (const float*)d_in[10];
    const float* w2      = (const float*)d_in[11];
    const float* b2      = (const float*)d_in[12];
    const float* w3      = (const float*)d_in[13];
    const float* b3      = (const float*)d_in[14];
    const float* fw1     = (const float*)d_in[15];
    const float* fb1     = (const float*)d_in[16];
    const float* fw2     = (const float*)d_in[17];
    const float* fb2     = (const float*)d_in[18];
    const float* fw3     = (const float*)d_in[19];
    const float* fb3     = (const float*)d_in[20];

    char* ws = (char*)d_ws;
    float*     zbuf = (float*)ws;                               // 1 MB
    _Float16*  hcat = (_Float16*)(ws + (1 << 20));              // 13.63 MB
    _Float16*  h1   = (_Float16*)(ws + 15 * (1 << 20));         // 1 MB
    _Float16*  h2   = (_Float16*)(ws + 16 * (1 << 20));         // 1 MB

    ode_kernel<<<64, 512, 0, stream>>>(past, xproj_w, xproj_b, z0_w, z0_b,
                                       ln_g, ln_b, w1, b1, w2, b2, w3, b3, zbuf);

    hcat_kernel<<<(2048 * 416) / 256, 256, 0, stream>>>(x_t, zbuf, tvals, hcat);

    gemm_f16<true,  true ><<<dim3(32, 4),  256, 0, stream>>>(hcat, fw1, fb1, h1, 2048, 256, 3328);
    gemm_f16<true,  true ><<<dim3(32, 4),  256, 0, stream>>>(h1,   fw2, fb2, h2, 2048, 256, 256);
    gemm_f16<false, false><<<dim3(32, 48), 256, 0, stream>>>(h2,   fw3, fb3, d_out, 2048, 3072, 256);
}

// Round 10
// 368.607 us; speedup vs baseline: 1.4244x; 1.4244x over previous
//
#include <hip/hip_runtime.h>
#include <math.h>

typedef _Float16 h8f16 __attribute__((ext_vector_type(8)));
typedef _Float16 h4f16 __attribute__((ext_vector_type(4)));
typedef _Float16 h2f16 __attribute__((ext_vector_type(2)));
typedef float f32x4 __attribute__((ext_vector_type(4)));

#define MFMA16(a, b, c) __builtin_amdgcn_mfma_f32_16x16x32_f16((a), (b), (c), 0, 0, 0)

__device__ __forceinline__ float silu_f(float v) {
    return v * __builtin_amdgcn_rcpf(1.0f + __expf(-v));
}

// Bare barrier: writer-side LDS completion + s_barrier (no vmcnt drain).
__device__ __forceinline__ void bar_lds() {
    asm volatile("s_waitcnt lgkmcnt(0)" ::: "memory");
    __builtin_amdgcn_s_barrier();
    __builtin_amdgcn_sched_barrier(0);
}

// ---------------------------------------------------------------------------
// FAT kernel, 200 blocks x 512 threads:
//   blocks   0..127 : ODE mega-kernel (v6 path, verbatim; proven 258 us)
//   blocks 128..191 : gemm1x: h1pre = x_t @ fw1[:, :3072].T  (f32 partials)
//   blocks 192..199 : temb:   tbuf  = time-embedding (f16)
// The gemm1x/temb work is independent of the ODE result and hides entirely
// under the ODE's latency-bound 258 us (200 blocks <= 256 CUs).
// ---------------------------------------------------------------------------
__global__ __launch_bounds__(512, 1) void fat_kernel(
    const float* __restrict__ past,
    const float* __restrict__ xproj_w, const float* __restrict__ xproj_b,
    const float* __restrict__ z0_w, const float* __restrict__ z0_b,
    const float* __restrict__ ln_g, const float* __restrict__ ln_b,
    const float* __restrict__ w1, const float* __restrict__ b1,
    const float* __restrict__ w2, const float* __restrict__ b2,
    const float* __restrict__ w3, const float* __restrict__ b3,
    const float* __restrict__ x_t, const float* __restrict__ fw1,
    const int* __restrict__ tvals,
    float* __restrict__ zbuf, float* __restrict__ h1pre,
    _Float16* __restrict__ tbuf)
{
    __shared__ union {
        struct {
            _Float16 hbuf[16][136];
            _Float16 h1S[16][136];
            _Float16 h2S[16][136];
            float    pS[16][33];
            float    x0S[16][128];
            float    zS0[16][129];
        } ode;
        struct {
            _Float16 aS[128][40];
            _Float16 wS[64][40];
        } gx;
    } sm;

    const int tid = threadIdx.x;

    if (blockIdx.x >= 192) {
        // ================= temb path: tbuf[b][0:128] =================
        const int t = blockIdx.x - 192;
        for (int c = 0; c < 8; ++c) {
            const int chunk = t * 512 + tid + c * 4096;   // 32768 chunks total
            const int b  = chunk >> 4;
            const int j0 = (chunk & 15) * 8;
            const float tv = (float)tvals[b];
            h8f16 v;
#pragma unroll
            for (int j = 0; j < 8; ++j) {
                const int jj  = j0 + j;
                const int idx = (jj < 64) ? jj : jj - 64;
                const float fr = expf(-9.210340371976184f * (float)idx * (1.0f / 63.0f));
                const float a  = tv * fr;
                v[j] = (_Float16)((jj < 64) ? sinf(a) : cosf(a));
            }
            *(h8f16*)&tbuf[(long)b * 128 + j0] = v;
        }
        return;
    }

    if (blockIdx.x >= 128) {
        // ============ gemm1x path: h1pre = x_t @ fw1[:, :3072].T ============
        // tile 128(M) x 64(N), K=3072; 8 waves each own 16 rows x 64 cols.
        const int g  = blockIdx.x - 128;          // 0..63
        const int mb = (g >> 2) * 128;
        const int nb = (g & 3) * 64;
        const int lane = tid & 63, wid = tid >> 6;
        const int lrow = lane & 15, lhi = lane >> 4;
        f32x4 acc[4];
#pragma unroll
        for (int nt = 0; nt < 4; ++nt) acc[nt] = (f32x4){0, 0, 0, 0};

        const int sra = tid >> 2, ska = (tid & 3) * 8;    // A stage: 128 rows x 32
        const int srw = tid >> 3, skw = (tid & 7) * 4;    // W stage: 64 rows x 32

        for (int k0 = 0; k0 < 3072; k0 += 32) {
            {
                const float* s = x_t + (long)(mb + sra) * 3072 + k0 + ska;
                const f32x4 u0 = *(const f32x4*)s;
                const f32x4 u1 = *(const f32x4*)(s + 4);
                h8f16 v;
#pragma unroll
                for (int j = 0; j < 4; ++j) { v[j] = (_Float16)u0[j]; v[4 + j] = (_Float16)u1[j]; }
                *(h8f16*)&sm.gx.aS[sra][ska] = v;
            }
            {
                const float* s = fw1 + (long)(nb + srw) * 3328 + k0 + skw;
                const f32x4 u = *(const f32x4*)s;
                h4f16 v;
#pragma unroll
                for (int j = 0; j < 4; ++j) v[j] = (_Float16)u[j];
                *(h4f16*)&sm.gx.wS[srw][skw] = v;
            }
            __syncthreads();
            const h8f16 a = *(const h8f16*)&sm.gx.aS[wid * 16 + lrow][lhi * 8];
#pragma unroll
            for (int nt = 0; nt < 4; ++nt) {
                const h8f16 bfr = *(const h8f16*)&sm.gx.wS[nt * 16 + lrow][lhi * 8];
                acc[nt] = MFMA16(a, bfr, acc[nt]);
            }
            __syncthreads();
        }
#pragma unroll
        for (int nt = 0; nt < 4; ++nt) {
            const int cc = nb + nt * 16 + lrow;
#pragma unroll
            for (int j = 0; j < 4; ++j) {
                const int rr = mb + wid * 16 + lhi * 4 + j;
                h1pre[(long)rr * 256 + cc] = acc[nt][j];
            }
        }
        return;
    }

    // ===================== ODE path (v6, verbatim) =====================
    _Float16 (&hbuf)[16][136] = sm.ode.hbuf;
    _Float16 (&h1S)[16][136]  = sm.ode.h1S;
    _Float16 (&h2S)[16][136]  = sm.ode.h2S;
    float    (&pS)[16][33]    = sm.ode.pS;
    float    (&x0S)[16][128]  = sm.ode.x0S;
    float    (&zS0)[16][129]  = sm.ode.zS0;

    const int wid  = tid >> 6;
    const int lane = tid & 63;
    const int lrow = lane & 15;
    const int lhi  = lane >> 4;
    const int b0   = blockIdx.x * 16;
    const int nc   = wid * 16 + lrow;
    const int koff = lhi * 8;

    // ---- weights into register B-fragments; gamma folded into W1a ----
    h8f16 w1f[4], wcf, w2f[4], w3f[4];
    float b1t, b2r, b3r;
    {
#pragma unroll
        for (int ks = 0; ks < 4; ++ks) {
            h8f16 v1, v2, v3;
#pragma unroll
            for (int j = 0; j < 8; ++j) {
                const int k = ks * 32 + koff + j;
                v1[j] = (_Float16)(w1[nc * 256 + k] * ln_g[k]);
                v2[j] = (_Float16)w2[nc * 128 + k];
                v3[j] = (_Float16)w3[nc * 128 + k];
            }
            w1f[ks] = v1; w2f[ks] = v2; w3f[ks] = v3;
        }
        float wc[8] = {0, 0, 0, 0, 0, 0, 0, 0};
        float bc = 0.0f, bb = 0.0f;
        const float* w1a = w1 + nc * 256;
        const float* w1b = w1a + 128;
#pragma unroll 4
        for (int k = 0; k < 128; ++k) {
            const float a = w1b[k];
            bc += a * xproj_b[k];
            bb += w1a[k] * ln_b[k];
            const float* xr = xproj_w + k * 32 + koff;
#pragma unroll
            for (int j = 0; j < 8; ++j) wc[j] += a * xr[j];
        }
        h8f16 v;
#pragma unroll
        for (int j = 0; j < 8; ++j) v[j] = (_Float16)wc[j];
        wcf = v;
        b1t = b1[nc] + bc + bb;
        b2r = b2[nc]; b3r = b3[nc];
    }

    // ---- prologue: z0 = (past[:,0,:] @ xw.T + xb) @ z0w.T + z0b (f32) ----
    if (tid < 512) {
        pS[tid >> 5][tid & 31] = past[(long)(b0 + (tid >> 5)) * 16384 + (tid & 31)];
    }
    __syncthreads();
    {
        const int r  = tid >> 5;
        const int c0 = (tid & 31) * 4;
#pragma unroll
        for (int cc = 0; cc < 4; ++cc) {
            const int kc = c0 + cc;
            float s = xproj_b[kc];
            const float* xr = xproj_w + kc * 32;
#pragma unroll
            for (int c = 0; c < 32; ++c) s += pS[r][c] * xr[c];
            x0S[r][kc] = s;
        }
    }
    __syncthreads();
    {
        const int nn = tid & 127;
        const int r0 = (tid >> 7) * 4;
        for (int p = 0; p < 4; ++p) {
            const int r = r0 + p;
            float s = z0_b[nn];
            const float* zr = z0_w + nn * 128;
            for (int k = 0; k < 128; ++k) s += x0S[r][k] * zr[k];
            zS0[r][nn] = s;
        }
    }
    __syncthreads();

    // ---- z cached per-lane in C-frag layout (rows 4*lhi+j, col nc) ----
    float zc[4], krk[4];
#pragma unroll
    for (int j = 0; j < 4; ++j) {
        zc[j] = zS0[4 * lhi + j][nc];
        hbuf[4 * lhi + j][nc] = (_Float16)zc[j];
    }

    const float DT = 1.0f / 32.0f;

    // ---- bx streaming (global loads; never vmcnt-drained in-loop) ----
    f32x4 s0a, s0b, s1a, s1b;
    auto stage = [&](int e) {
        const float pos = (float)e * 7.984375f;   // e*(511/64), exact
        const int i0 = (int)pos;
        const int i1 = (i0 < 511) ? i0 + 1 : 511;
        const float* base = past + (long)(b0 + lrow) * 16384;
        const float* p0 = base + i0 * 32 + koff;
        const float* p1 = base + i1 * 32 + koff;
        s0a = *(const f32x4*)p0; s0b = *(const f32x4*)(p0 + 4);
        s1a = *(const f32x4*)p1; s1b = *(const f32x4*)(p1 + 4);
    };
    auto blend = [&](int e) -> h8f16 {
        const float pos = (float)e * 7.984375f;
        const float w = pos - floorf(pos);
        h8f16 r;
#pragma unroll
        for (int j = 0; j < 4; ++j) {
            r[j]     = (_Float16)(s0a[j] + w * (s1a[j] - s0a[j]));
            r[4 + j] = (_Float16)(s0b[j] + w * (s1b[j] - s0b[j]));
        }
        return r;
    };

    const h2f16 one2 = {(_Float16)1.0f, (_Float16)1.0f};

    auto phaseA = [&](h8f16 bxc) {
        h8f16 xf[4];
#pragma unroll
        for (int ks = 0; ks < 4; ++ks)
            xf[ks] = *(const h8f16*)&hbuf[lrow][ks * 32 + koff];
        float s0 = 0.f, s1 = 0.f, q0 = 0.f, q1 = 0.f;
#pragma unroll
        for (int ks = 0; ks < 4; ++ks) {
#pragma unroll
            for (int p = 0; p < 4; ++p) {
                const h2f16 x2 = {xf[ks][2 * p], xf[ks][2 * p + 1]};
                if (p & 1) {
                    s1 = __builtin_amdgcn_fdot2(x2, one2, s1, false);
                    q1 = __builtin_amdgcn_fdot2(x2, x2, q1, false);
                } else {
                    s0 = __builtin_amdgcn_fdot2(x2, one2, s0, false);
                    q0 = __builtin_amdgcn_fdot2(x2, x2, q0, false);
                }
            }
        }
        float s = s0 + s1, q = q0 + q1;
        s += __shfl_xor(s, 16); q += __shfl_xor(q, 16);
        s += __shfl_xor(s, 32); q += __shfl_xor(q, 32);
        const float mu  = s * (1.0f / 128.0f);
        const float var = q * (1.0f / 128.0f) - mu * mu;
        const float inv = 1.0f / sqrtf(var + 1e-5f);
        const _Float16 ih = (_Float16)inv;
        const _Float16 mh = (_Float16)(-mu * inv);
        h8f16 ip, mp;
#pragma unroll
        for (int j = 0; j < 8; ++j) { ip[j] = ih; mp[j] = mh; }
        f32x4 acc = {0, 0, 0, 0};
#pragma unroll
        for (int ks = 0; ks < 4; ++ks) {
            const h8f16 az = xf[ks] * ip + mp;   // packed f16 LN-apply
            acc = MFMA16(az, w1f[ks], acc);
        }
        acc = MFMA16(bxc, wcf, acc);
#pragma unroll
        for (int j = 0; j < 4; ++j)
            h1S[4 * lhi + j][nc] = (_Float16)silu_f(acc[j] + b1t);
    };
    auto phaseB = [&]() {
        f32x4 acc = {0, 0, 0, 0};
#pragma unroll
        for (int ks = 0; ks < 4; ++ks) {
            const h8f16 a = *(const h8f16*)&h1S[lrow][ks * 32 + koff];
            acc = MFMA16(a, w2f[ks], acc);
        }
#pragma unroll
        for (int j = 0; j < 4; ++j)
            h2S[4 * lhi + j][nc] = (_Float16)silu_f(acc[j] + b2r);
    };
    auto phaseC = [&]() -> f32x4 {
        f32x4 acc = {0, 0, 0, 0};
#pragma unroll
        for (int ks = 0; ks < 4; ++ks) {
            const h8f16 a = *(const h8f16*)&h2S[lrow][ks * 32 + koff];
            acc = MFMA16(a, w3f[ks], acc);
        }
#pragma unroll
        for (int j = 0; j < 4; ++j) acc[j] += b3r;
        return acc;
    };

    stage(0);
    h8f16 bxc = blend(0);
    __syncthreads();

#pragma unroll 1
    for (int st = 0; st < 32; ++st) {
        const int e1 = 2 * st + 1, e2 = 2 * st + 2;
        // ---- sub0: k1 ----
        phaseA(bxc);
        stage(e1);
        bar_lds();
        phaseB(); bar_lds();
        {
            const f32x4 k = phaseC();
#pragma unroll
            for (int j = 0; j < 4; ++j) {
                krk[j] = k[j];
                hbuf[4 * lhi + j][nc] = (_Float16)(zc[j] + 0.5f * DT * k[j]);
            }
        }
        bar_lds();
        // ---- sub1: k2 ----
        bxc = blend(e1);
        phaseA(bxc); bar_lds();
        phaseB(); bar_lds();
        {
            const f32x4 k = phaseC();
#pragma unroll
            for (int j = 0; j < 4; ++j) {
                krk[j] += 2.0f * k[j];
                hbuf[4 * lhi + j][nc] = (_Float16)(zc[j] + 0.5f * DT * k[j]);
            }
        }
        bar_lds();
        // ---- sub2: k3 ----
        phaseA(bxc);
        stage(e2);
        bar_lds();
        phaseB(); bar_lds();
        {
            const f32x4 k = phaseC();
#pragma unroll
            for (int j = 0; j < 4; ++j) {
                krk[j] += 2.0f * k[j];
                hbuf[4 * lhi + j][nc] = (_Float16)(zc[j] + DT * k[j]);
            }
        }
        bar_lds();
        // ---- sub3: k4 + z update ----
        bxc = blend(e2);
        phaseA(bxc); bar_lds();
        phaseB(); bar_lds();
        {
            const f32x4 k = phaseC();
#pragma unroll
            for (int j = 0; j < 4; ++j) {
                zc[j] += (DT / 6.0f) * (krk[j] + k[j]);
                hbuf[4 * lhi + j][nc] = (_Float16)zc[j];
            }
        }
        bar_lds();
    }

#pragma unroll
    for (int j = 0; j < 4; ++j)
        zbuf[(long)(b0 + 4 * lhi + j) * 128 + nc] = zc[j];
}

// ---------------------------------------------------------------------------
// gemm1c: h1 = silu(h1pre + [cond(f32)|temb(f16)] @ fw1[:,3072:].T + fb1)
// M=2048 N=256 K=256. grid (32,4) x 256 threads.
// ---------------------------------------------------------------------------
__global__ __launch_bounds__(256) void gemm1c_kernel(
    const float* __restrict__ cond, const _Float16* __restrict__ tbuf,
    const float* __restrict__ fw1, const float* __restrict__ fb1,
    const float* __restrict__ h1pre, _Float16* __restrict__ h1)
{
    __shared__ _Float16 aS[64][40];
    __shared__ _Float16 wS[64][40];
    const int mb = blockIdx.x * 64, nb = blockIdx.y * 64;
    const int tid = threadIdx.x, lane = tid & 63, wq = tid >> 6;
    const int lrow = lane & 15, lhi = lane >> 4;
    f32x4 acc[4];
#pragma unroll
    for (int nt = 0; nt < 4; ++nt) acc[nt] = (f32x4){0, 0, 0, 0};

    const int sr = tid >> 2;
    const int sk = (tid & 3) * 8;

    for (int k0 = 0; k0 < 256; k0 += 32) {
        if (k0 < 128) {
            const float* s = cond + (long)(mb + sr) * 128 + k0 + sk;
            const f32x4 u0 = *(const f32x4*)s;
            const f32x4 u1 = *(const f32x4*)(s + 4);
            h8f16 v;
#pragma unroll
            for (int j = 0; j < 4; ++j) { v[j] = (_Float16)u0[j]; v[4 + j] = (_Float16)u1[j]; }
            *(h8f16*)&aS[sr][sk] = v;
        } else {
            *(h8f16*)&aS[sr][sk] =
                *(const h8f16*)&tbuf[(long)(mb + sr) * 128 + (k0 - 128) + sk];
        }
        {
            const float* s = fw1 + (long)(nb + sr) * 3328 + 3072 + k0 + sk;
            h8f16 v;
#pragma unroll
            for (int j = 0; j < 8; ++j) v[j] = (_Float16)s[j];
            *(h8f16*)&wS[sr][sk] = v;
        }
        __syncthreads();
        const h8f16 a = *(const h8f16*)&aS[wq * 16 + lrow][lhi * 8];
#pragma unroll
        for (int nt = 0; nt < 4; ++nt) {
            const h8f16 bfr = *(const h8f16*)&wS[nt * 16 + lrow][lhi * 8];
            acc[nt] = MFMA16(a, bfr, acc[nt]);
        }
        __syncthreads();
    }

#pragma unroll
    for (int nt = 0; nt < 4; ++nt) {
        const int cc = nb + nt * 16 + lrow;
        const float bv = fb1[cc];
#pragma unroll
        for (int j = 0; j < 4; ++j) {
            const int rr = mb + wq * 16 + lhi * 4 + j;
            const float v = acc[nt][j] + h1pre[(long)rr * 256 + cc] + bv;
            h1[(long)rr * 256 + cc] = (_Float16)silu_f(v);
        }
    }
}

// ---------------------------------------------------------------------------
// Generic f16-MFMA GEMM: out(M,N) = [silu](A(M,K) @ W(N,K).T + bias)
// ---------------------------------------------------------------------------
template <bool SILU, bool OUT_F16>
__global__ __launch_bounds__(256) void gemm_f16(
    const _Float16* __restrict__ A, const float* __restrict__ W,
    const float* __restrict__ bias, void* __restrict__ out,
    int M, int N, int K)
{
    __shared__ _Float16 aS[64][40];
    __shared__ _Float16 wS[64][40];
    const int mb = blockIdx.x * 64, nb = blockIdx.y * 64;
    const int tid = threadIdx.x, lane = tid & 63, wq = tid >> 6;
    const int lrow = lane & 15, lhi = lane >> 4;
    f32x4 acc[4];
#pragma unroll
    for (int nt = 0; nt < 4; ++nt) acc[nt] = (f32x4){0, 0, 0, 0};

    const int sr = tid >> 2;
    const int sk = (tid & 3) * 8;

    for (int k0 = 0; k0 < K; k0 += 32) {
        {
            h8f16 v = *(const h8f16*)&A[(long)(mb + sr) * K + k0 + sk];
            *(h8f16*)&aS[sr][sk] = v;
        }
        {
            const float* s = &W[(long)(nb + sr) * K + k0 + sk];
            h8f16 v;
#pragma unroll
            for (int j = 0; j < 8; ++j) v[j] = (_Float16)s[j];
            *(h8f16*)&wS[sr][sk] = v;
        }
        __syncthreads();
        h8f16 a = *(const h8f16*)&aS[wq * 16 + lrow][lhi * 8];
#pragma unroll
        for (int nt = 0; nt < 4; ++nt) {
            h8f16 bfr = *(const h8f16*)&wS[nt * 16 + lrow][lhi * 8];
            acc[nt] = MFMA16(a, bfr, acc[nt]);
        }
        __syncthreads();
    }

#pragma unroll
    for (int nt = 0; nt < 4; ++nt) {
        const int cc = nb + nt * 16 + lrow;
        const float bv = bias[cc];
#pragma unroll
        for (int j = 0; j < 4; ++j) {
            const int rr = mb + wq * 16 + lhi * 4 + j;
            float v = acc[nt][j] + bv;
            if (SILU) v = silu_f(v);
            if (OUT_F16) ((_Float16*)out)[(long)rr * N + cc] = (_Float16)v;
            else         ((float*)out)[(long)rr * N + cc] = v;
        }
    }
}

// ---------------------------------------------------------------------------
extern "C" void kernel_launch(void* const* d_in, const int* in_sizes, int n_in,
                              void* d_out, int out_size, void* d_ws, size_t ws_size,
                              hipStream_t stream)
{
    const float* x_t     = (const float*)d_in[0];
    const float* past    = (const float*)d_in[1];
    const int*   tvals   = (const int*)d_in[2];
    const float* xproj_w = (const float*)d_in[3];
    const float* xproj_b = (const float*)d_in[4];
    const float* z0_w    = (const float*)d_in[5];
    const float* z0_b    = (const float*)d_in[6];
    const float* ln_g    = (const float*)d_in[7];
    const float* ln_b    = (const float*)d_in[8];
    const float* w1      = (const float*)d_in[9];
    const float* b1      = (const float*)d_in[10];
    const float* w2      = (const float*)d_in[11];
    const float* b2      = (const float*)d_in[12];
    const float* w3      = (const float*)d_in[13];
    const float* b3      = (const float*)d_in[14];
    const float* fw1     = (const float*)d_in[15];
    const float* fb1     = (const float*)d_in[16];
    const float* fw2     = (const float*)d_in[17];
    const float* fb2     = (const float*)d_in[18];
    const float* fw3     = (const float*)d_in[19];
    const float* fb3     = (const float*)d_in[20];

    char* ws = (char*)d_ws;
    float*     zbuf  = (float*)ws;                       // 1 MB   (B*128 f32)
    _Float16*  tbuf  = (_Float16*)(ws + (1 << 20));      // 0.5 MB (B*128 f16)
    float*     h1pre = (float*)(ws + 2 * (1 << 20));     // 2 MB   (B*256 f32)
    _Float16*  h1    = (_Float16*)(ws + 4 * (1 << 20));  // 1 MB
    _Float16*  h2    = (_Float16*)(ws + 5 * (1 << 20));  // 1 MB

    fat_kernel<<<200, 512, 0, stream>>>(past, xproj_w, xproj_b, z0_w, z0_b,
                                        ln_g, ln_b, w1, b1, w2, b2, w3, b3,
                                        x_t, fw1, tvals, zbuf, h1pre, tbuf);

    gemm1c_kernel<<<dim3(32, 4), 256, 0, stream>>>(zbuf, tbuf, fw1, fb1, h1pre, h1);

    gemm_f16<true,  true ><<<dim3(32, 4),  256, 0, stream>>>(h1, fw2, fb2, h2, 2048, 256, 256);
    gemm_f16<false, false><<<dim3(32, 48), 256, 0, stream>>>(h2, fw3, fb3, d_out, 2048, 3072, 256);
}